// Round 4
// baseline (3449.533 us; speedup 1.0000x reference)
//
#include <hip/hip_runtime.h>
#include <math.h>

// Problem constants
#define Bq   128
#define Tq   512
#define Iq   300   // input dim
#define Hq   150   // hidden per dir
#define G3   450   // 3*H
#define Kq   6
#define Cq   300
#define D2   300   // 2*H
#define THq  20
#define CLSq 5

// ---------------------------------------------------------------------------
// Kernel 1: gi GEMM, 128x128 block tile, 8x8 per-thread register tile, fp32.
// ---------------------------------------------------------------------------
#define BK 16
#define LDP 132   // padded LDS row stride

__global__ __launch_bounds__(256) void gi_gemm(
    const float* __restrict__ x,
    const float* __restrict__ Wf, const float* __restrict__ bf,
    const float* __restrict__ Wb, const float* __restrict__ bb,
    float* __restrict__ gic,     // [2][B][TCr][450]
    int t0f, int t0b, int tcShift)
{
    const int dir = blockIdx.z;
    const float* W    = dir ? Wb : Wf;
    const float* bias = dir ? bb : bf;
    const int t0 = dir ? t0b : t0f;
    const int TCr = 1 << tcShift;
    float* outbase = gic + (size_t)dir * Bq * TCr * G3;

    const int m0 = blockIdx.y * 128;
    const int n0 = blockIdx.x * 128;
    const int tid = threadIdx.x;
    const int tx = tid & 15;    // n-group
    const int ty = tid >> 4;    // m-octet

    __shared__ __align__(16) float As[BK][LDP];
    __shared__ __align__(16) float Bs[BK][LDP];

    const int srow = tid >> 2;      // 0..63 (+64 for q=1)
    const int skq  = tid & 3;

    float acc[8][8];
    #pragma unroll
    for (int i = 0; i < 8; ++i)
        #pragma unroll
        for (int j = 0; j < 8; ++j) acc[i][j] = 0.f;

    for (int k0 = 0; k0 < Iq; k0 += BK) {
        #pragma unroll
        for (int q = 0; q < 2; ++q) {
            const int m = q * 64 + srow;            // local m in tile
            const int r = m0 + m;                   // global row
            const int bb_ = r >> tcShift;
            const int lt = r & (TCr - 1);
            const int kk = k0 + skq * 4;
            float4 av = make_float4(0.f, 0.f, 0.f, 0.f);
            if (kk < Iq)
                av = *(const float4*)(x + ((size_t)bb_ * Tq + t0 + lt) * Iq + kk);
            As[skq*4+0][m] = av.x; As[skq*4+1][m] = av.y;
            As[skq*4+2][m] = av.z; As[skq*4+3][m] = av.w;

            const int n = q * 64 + srow;
            float4 bv = make_float4(0.f, 0.f, 0.f, 0.f);
            if ((n0 + n < G3) && (kk < Iq))
                bv = *(const float4*)(W + (size_t)(n0 + n) * Iq + kk);
            Bs[skq*4+0][n] = bv.x; Bs[skq*4+1][n] = bv.y;
            Bs[skq*4+2][n] = bv.z; Bs[skq*4+3][n] = bv.w;
        }
        __syncthreads();

        #pragma unroll
        for (int k = 0; k < BK; ++k) {
            float4 a0 = *(const float4*)&As[k][ty * 8];
            float4 a1 = *(const float4*)&As[k][ty * 8 + 4];
            float4 b0 = *(const float4*)&Bs[k][tx * 4];
            float4 b1 = *(const float4*)&Bs[k][64 + tx * 4];
            float aa[8] = {a0.x,a0.y,a0.z,a0.w,a1.x,a1.y,a1.z,a1.w};
            float bbv[8] = {b0.x,b0.y,b0.z,b0.w,b1.x,b1.y,b1.z,b1.w};
            #pragma unroll
            for (int i = 0; i < 8; ++i)
                #pragma unroll
                for (int j = 0; j < 8; ++j)
                    acc[i][j] += aa[i] * bbv[j];
        }
        __syncthreads();
    }

    #pragma unroll
    for (int i = 0; i < 8; ++i) {
        const int r = m0 + ty * 8 + i;              // global row
        float* orow = outbase + (size_t)r * G3;
        #pragma unroll
        for (int g = 0; g < 2; ++g) {
            const int n = n0 + g * 64 + tx * 4;
            if (n + 3 < G3) {
                float4 v = make_float4(acc[i][g*4+0] + bias[n],
                                       acc[i][g*4+1] + bias[n+1],
                                       acc[i][g*4+2] + bias[n+2],
                                       acc[i][g*4+3] + bias[n+3]);
                *(float4*)(orow + n) = v;
            } else {
                #pragma unroll
                for (int j = 0; j < 4; ++j)
                    if (n + j < G3) orow[n + j] = acc[i][g*4+j] + bias[n+j];
            }
        }
    }
}

// ---------------------------------------------------------------------------
// Kernel 2: GRU recurrence, one TCr-step chunk. One block per (b, dir),
// 256 threads. Thread j (<225) caches Whh rows 2j and 2j+1 (2x150 fp32) in
// registers; one h-fetch from LDS feeds both rows (halves LDS-pipe traffic,
// which R3 counters showed is the binding pipe: VALUBusy 49%, conflicts 0,
// step time == ds_read_b128 issue model).
// ---------------------------------------------------------------------------
__global__ __launch_bounds__(256, 1) void gru_rec(
    const float* __restrict__ gic,     // [2][B][TCr][450]
    const float* __restrict__ Whh_f, const float* __restrict__ bhh_f,
    const float* __restrict__ Whh_b, const float* __restrict__ bhh_b,
    float* __restrict__ hstate,        // [2][B][150]
    float* __restrict__ seq,           // [B][T][300]
    int chunk, int tcShift)
{
    const int TCr = 1 << tcShift;
    const int bid = blockIdx.x;
    const int dir = bid & 1;
    const int b   = bid >> 1;
    const float* Whh = dir ? Whh_b : Whh_f;
    const float* bhh = dir ? bhh_b : bhh_f;
    const int tid = threadIdx.x;
    const int j   = tid;               // row pair index (valid < 225)
    const bool act = (j < 225);

    __shared__ __align__(16) float stage[64 * 150];  // 38.4 KB W-staging
    __shared__ __align__(16) float4 hbuf4[38];       // h padded to 152 floats
    __shared__ float gh_s[456];
    __shared__ float gi_s[456];
    float* hbuf = (float*)hbuf4;

    float w0[152], w1[152];

    // --- load Whh rows 2j, 2j+1 into registers via coalesced LDS staging
    for (int c = 0; c < 8; ++c) {
        const int r0 = c * 64;                      // rows r0..r0+63 (450 total)
        const int nrows = (r0 + 64 <= G3) ? 64 : (G3 - r0);
        const int nel = nrows * 150;
        __syncthreads();
        for (int idx = tid * 4; idx < nel; idx += 256 * 4)
            *(float4*)&stage[idx] = *(const float4*)(Whh + (size_t)r0 * 150 + idx);
        __syncthreads();
        // thread j owns rows 2j,2j+1; both land in chunk c iff c*32 <= j < c*32+32
        if (act && (j >> 5) == c) {
            const int rl = 2 * j - r0;              // 0..62 even
            #pragma unroll
            for (int i = 0; i < 150; i += 2) {
                float2 v0 = *(const float2*)&stage[rl * 150 + i];
                w0[i] = v0.x; w0[i + 1] = v0.y;
            }
            if (2 * j + 1 < G3) {
                #pragma unroll
                for (int i = 0; i < 150; i += 2) {
                    float2 v1 = *(const float2*)&stage[(rl + 1) * 150 + i];
                    w1[i] = v1.x; w1[i + 1] = v1.y;
                }
            }
        }
    }
    w0[150] = 0.f; w0[151] = 0.f;
    w1[150] = 0.f; w1[151] = 0.f;
    const float bh0 = act ? bhh[2 * j]     : 0.f;
    const float bh1 = act ? bhh[2 * j + 1] : 0.f;

    float* hs = hstate + (size_t)(dir * Bq + b) * Hq;
    if (tid < 152) hbuf[tid] = (tid < Hq && chunk > 0) ? hs[tid] : 0.f;
    __syncthreads();

    const float* gib = gic + (size_t)(dir * Bq + b) * TCr * G3;
    const int t0 = dir ? (Tq - TCr * (chunk + 1)) : (chunk * TCr);
    float* seqb = seq + (size_t)b * Tq * D2 + dir * Hq;

    int lt = dir ? (TCr - 1) : 0;
    float2 gval = make_float2(0.f, 0.f);
    if (act) gval = *(const float2*)(gib + (size_t)lt * G3 + 2 * j);

    for (int s = 0; s < TCr; ++s) {
        const int ltn = dir ? (TCr - 2 - s) : (s + 1);
        float2 gnext = make_float2(0.f, 0.f);
        if (s + 1 < TCr && act)
            gnext = *(const float2*)(gib + (size_t)ltn * G3 + 2 * j);

        if (act) {
            float acc0 = bh0, acc1 = bh1;
            #pragma unroll
            for (int q = 0; q < 38; ++q) {
                float4 hv = hbuf4[q];   // wave-uniform broadcast read
                acc0 += hv.x * w0[q*4+0] + hv.y * w0[q*4+1]
                      + hv.z * w0[q*4+2] + hv.w * w0[q*4+3];
                acc1 += hv.x * w1[q*4+0] + hv.y * w1[q*4+1]
                      + hv.z * w1[q*4+2] + hv.w * w1[q*4+3];
            }
            *(float2*)&gh_s[2 * j] = make_float2(acc0, acc1);
            *(float2*)&gi_s[2 * j] = gval;
        }
        __syncthreads();

        if (tid < Hq) {
            const float r = 1.f / (1.f + __expf(-(gi_s[tid]       + gh_s[tid])));
            const float z = 1.f / (1.f + __expf(-(gi_s[150 + tid] + gh_s[150 + tid])));
            const float nv = tanhf(gi_s[300 + tid] + r * gh_s[300 + tid]);
            const float hn = (1.f - z) * nv + z * hbuf[tid];
            hbuf[tid] = hn;
            seqb[(size_t)(t0 + lt) * D2 + tid] = hn;
        }
        __syncthreads();

        gval = gnext;
        lt = ltn;
    }

    if (tid < Hq) hs[tid] = hbuf[tid];
}

// ---------------------------------------------------------------------------
// Kernel 3a: ctxW[k][d] = battn[k][d] + sum_c attn_context[k][c]*Wattn[k][c][d]
// ---------------------------------------------------------------------------
__global__ void ctxw_kernel(
    const float* __restrict__ attn_context,
    const float* __restrict__ Wattn,
    const float* __restrict__ battn,
    float* __restrict__ ctxW)
{
    const int o = blockIdx.x * 256 + threadIdx.x;
    if (o >= Kq * D2) return;
    const int k = o / D2, d = o % D2;
    float acc = battn[o];
    const float* Wp = Wattn + ((size_t)k * (Cq + D2)) * D2 + d;
    for (int c = 0; c < Cq; ++c)
        acc += attn_context[k * Cq + c] * Wp[(size_t)c * D2];
    ctxW[o] = acc;
}

// ---------------------------------------------------------------------------
// Kernel 3b: context[b][k][:] = tanh(ctxW[k] + hidden[b] @ Wattn[k,300:,:])
// ---------------------------------------------------------------------------
__global__ __launch_bounds__(256) void ctx_compute(
    const float* __restrict__ seq,
    const float* __restrict__ Wattn,
    const float* __restrict__ ctxW,
    float* __restrict__ context,      // [B][6][300]
    float* __restrict__ normsq)       // [B][6]
{
    const int b = blockIdx.x;
    const int k = blockIdx.y;
    const int tid = threadIdx.x;
    const int lane = tid & 63, wv = tid >> 6;

    __shared__ float hb[304];
    __shared__ float red[4];

    for (int i = tid; i < D2; i += 256)
        hb[i] = (i < Hq) ? seq[((size_t)b * Tq + (Tq - 1)) * D2 + i]
                         : seq[(size_t)b * Tq * D2 + i];
    __syncthreads();

    float ssq = 0.f;
    for (int d = tid; d < D2; d += 256) {
        float acc = ctxW[k * D2 + d];
        const float* Wp = Wattn + ((size_t)k * (Cq + D2) + Cq) * D2 + d;
        for (int jj = 0; jj < D2; ++jj)
            acc += hb[jj] * Wp[(size_t)jj * D2];
        const float c = tanhf(acc);
        context[((size_t)b * Kq + k) * D2 + d] = c;
        ssq += c * c;
    }
    for (int off = 32; off > 0; off >>= 1) ssq += __shfl_xor(ssq, off, 64);
    if (lane == 0) red[wv] = ssq;
    __syncthreads();
    if (tid == 0) normsq[b * Kq + k] = red[0] + red[1] + red[2] + red[3];
}

// ---------------------------------------------------------------------------
// Kernel 3c: gram regularizer per b
// ---------------------------------------------------------------------------
__global__ __launch_bounds__(256) void gram_kernel(
    const float* __restrict__ context,
    const float* __restrict__ normsq,
    float* __restrict__ regbuf)
{
    const int b = blockIdx.x;
    const int tid = threadIdx.x;
    __shared__ float ctx[Kq * D2];
    __shared__ float Gm[36];

    for (int o = tid; o < Kq * D2; o += 256)
        ctx[o] = context[(size_t)b * Kq * D2 + o];
    __syncthreads();

    if (tid < 36) {
        const int k = tid / 6, jj = tid % 6;
        float g = 0.f;
        for (int d = 0; d < D2; ++d)
            g += ctx[k * D2 + d] * ctx[jj * D2 + d];
        const float nk = fmaxf(sqrtf(normsq[b * Kq + k]), 1e-12f);
        const float nj = fmaxf(sqrtf(normsq[b * Kq + jj]), 1e-12f);
        g /= (nk * nj);
        const float diff = g - ((k == jj) ? 1.f : 0.f);
        Gm[tid] = diff * diff;
    }
    __syncthreads();
    if (tid == 0) {
        float s = 0.f;
        for (int i = 0; i < 36; ++i) s += Gm[i];
        regbuf[b] = sqrtf(s);
    }
}

// ---------------------------------------------------------------------------
// Kernel 4a: energy[b][t][k] = seq[b][t] . context[b][k]   grid (8, B)
// ---------------------------------------------------------------------------
__global__ __launch_bounds__(256) void energy_kernel(
    const float* __restrict__ seq,
    const float* __restrict__ context,
    float* __restrict__ en)           // [B][512][6]
{
    const int tc = blockIdx.x;
    const int b  = blockIdx.y;
    const int tid = threadIdx.x;
    const int lane = tid & 63, wv = tid >> 6;

    __shared__ float ctx[Kq * D2];
    for (int o = tid; o < Kq * D2; o += 256)
        ctx[o] = context[(size_t)b * Kq * D2 + o];
    __syncthreads();

    const float* seqb = seq + (size_t)b * Tq * D2;
    for (int s = 0; s < 16; ++s) {
        const int tt = tc * 64 + s * 4 + wv;
        float acc[Kq] = {0.f,0.f,0.f,0.f,0.f,0.f};
        for (int d = lane; d < D2; d += 64) {
            const float sv = seqb[(size_t)tt * D2 + d];
            #pragma unroll
            for (int k = 0; k < Kq; ++k) acc[k] += sv * ctx[k * D2 + d];
        }
        #pragma unroll
        for (int k = 0; k < Kq; ++k) {
            float v = acc[k];
            for (int off = 32; off > 0; off >>= 1) v += __shfl_xor(v, off, 64);
            if (lane == 0) en[((size_t)b * Tq + tt) * Kq + k] = v;
        }
    }
}

// ---------------------------------------------------------------------------
// Kernel 4b: softmax over t per (b,k), in-place on en.  grid (B)
// ---------------------------------------------------------------------------
__global__ __launch_bounds__(256) void softmax_kernel(float* __restrict__ en)
{
    const int b = blockIdx.x;
    const int tid = threadIdx.x;
    const int lane = tid & 63, wv = tid >> 6;
    __shared__ float es[Tq * Kq];
    __shared__ float red[8];

    for (int o = tid; o < Tq * Kq; o += 256)
        es[o] = en[(size_t)b * Tq * Kq + o];
    __syncthreads();

    for (int k = 0; k < Kq; ++k) {
        float m = -1e30f;
        for (int tt = tid; tt < Tq; tt += 256) m = fmaxf(m, es[tt * Kq + k]);
        for (int off = 32; off > 0; off >>= 1) m = fmaxf(m, __shfl_xor(m, off, 64));
        if (lane == 0) red[wv] = m;
        __syncthreads();
        m = fmaxf(fmaxf(red[0], red[1]), fmaxf(red[2], red[3]));
        float ssum = 0.f;
        for (int tt = tid; tt < Tq; tt += 256) {
            const float e = __expf(es[tt * Kq + k] - m);
            es[tt * Kq + k] = e;
            ssum += e;
        }
        for (int off = 32; off > 0; off >>= 1) ssum += __shfl_xor(ssum, off, 64);
        if (lane == 0) red[4 + wv] = ssum;
        __syncthreads();
        const float inv = 1.f / (red[4] + red[5] + red[6] + red[7]);
        for (int tt = tid; tt < Tq; tt += 256) es[tt * Kq + k] *= inv;
        __syncthreads();
    }

    for (int o = tid; o < Tq * Kq; o += 256)
        en[(size_t)b * Tq * Kq + o] = es[o];
}

// ---------------------------------------------------------------------------
// Kernel 4c: pooled partials over 64-t chunks.  grid (8, B)
// ---------------------------------------------------------------------------
__global__ __launch_bounds__(256) void pooledp_kernel(
    const float* __restrict__ seq,
    const float* __restrict__ en,     // probs now
    float* __restrict__ partial)      // [B*8][1800]
{
    const int tc = blockIdx.x;
    const int b  = blockIdx.y;
    const int tid = threadIdx.x;
    const int lane = tid & 63, wv = tid >> 6;

    __shared__ float pr[64 * Kq];
    __shared__ float part[4][Kq * D2];   // 28.8 KB

    if (tid < 64 * Kq / 2) {
        pr[tid]       = en[((size_t)b * Tq + tc * 64) * Kq + tid];
        pr[tid + 192] = en[((size_t)b * Tq + tc * 64) * Kq + tid + 192];
    }
    __syncthreads();

    const float* seqb = seq + (size_t)b * Tq * D2;

    float pp[Kq][5];
    #pragma unroll
    for (int k = 0; k < Kq; ++k)
        #pragma unroll
        for (int q = 0; q < 5; ++q) pp[k][q] = 0.f;

    for (int s = 0; s < 16; ++s) {
        const int tl = s * 4 + wv;
        const int tt = tc * 64 + tl;
        float prr[Kq];
        #pragma unroll
        for (int k = 0; k < Kq; ++k) prr[k] = pr[tl * Kq + k];
        #pragma unroll
        for (int q = 0; q < 5; ++q) {
            const int d = lane + q * 64;
            const float sv = (d < D2) ? seqb[(size_t)tt * D2 + d] : 0.f;
            #pragma unroll
            for (int k = 0; k < Kq; ++k) pp[k][q] += prr[k] * sv;
        }
    }
    #pragma unroll
    for (int k = 0; k < Kq; ++k)
        #pragma unroll
        for (int q = 0; q < 5; ++q) {
            const int d = lane + q * 64;
            if (d < D2) part[wv][k * D2 + d] = pp[k][q];
        }
    __syncthreads();
    float* op = partial + ((size_t)b * 8 + tc) * (Kq * D2);
    for (int o = tid; o < Kq * D2; o += 256)
        op[o] = part[0][o] + part[1][o] + part[2][o] + part[3][o];
}

// ---------------------------------------------------------------------------
// Kernel 4d: final: pooled reduce -> topic -> logits -> softmax.  grid (B)
// ---------------------------------------------------------------------------
__global__ __launch_bounds__(256) void final_kernel(
    const float* __restrict__ partial,
    const float* __restrict__ Wtop,
    const float* __restrict__ btop,
    const float* __restrict__ Wout,
    const float* __restrict__ bout,
    float* __restrict__ outp)
{
    const int b = blockIdx.x;
    const int tid = threadIdx.x;
    __shared__ float pooled[Kq * D2];
    __shared__ float feats[Kq * THq];
    __shared__ float lsm[8];

    for (int o = tid; o < Kq * D2; o += 256) {
        float s = 0.f;
        #pragma unroll
        for (int c = 0; c < 8; ++c)
            s += partial[((size_t)b * 8 + c) * (Kq * D2) + o];
        pooled[o] = s;
    }
    __syncthreads();

    if (tid < Kq * THq) {
        const int k = tid / THq, hh = tid % THq;
        float acc = btop[tid];
        const float* wp = Wtop + (size_t)k * D2 * THq + hh;
        for (int d = 0; d < D2; ++d)
            acc += pooled[k * D2 + d] * wp[(size_t)d * THq];
        feats[tid] = fmaxf(acc, 0.f);
    }
    __syncthreads();

    if (tid < CLSq) {
        float acc = bout[tid];
        for (int f = 0; f < Kq * THq; ++f)
            acc += feats[f] * Wout[f * CLSq + tid];
        lsm[tid] = acc;
    }
    __syncthreads();
    if (tid < CLSq) {
        float m = lsm[0];
        for (int c = 1; c < CLSq; ++c) m = fmaxf(m, lsm[c]);
        float s = 0.f;
        for (int c = 0; c < CLSq; ++c) s += __expf(lsm[c] - m);
        outp[(size_t)b * CLSq + tid] = __expf(lsm[tid] - m) / s;
    }
}

// ---------------------------------------------------------------------------
// Kernel 5: reg = mean_b regbuf[b]  -> d_out[640]
// ---------------------------------------------------------------------------
__global__ void reg_final(const float* __restrict__ regbuf, float* __restrict__ outp)
{
    const int tid = threadIdx.x;   // 128 threads
    float v = regbuf[tid];
    for (int off = 32; off > 0; off >>= 1) v += __shfl_xor(v, off, 64);
    __shared__ float r2[2];
    if ((tid & 63) == 0) r2[tid >> 6] = v;
    __syncthreads();
    if (tid == 0) outp[Bq * CLSq] = (r2[0] + r2[1]) * (1.f / (float)Bq);
}

// ---------------------------------------------------------------------------
extern "C" void kernel_launch(void* const* d_in, const int* in_sizes, int n_in,
                              void* d_out, int out_size, void* d_ws, size_t ws_size,
                              hipStream_t stream)
{
    const float* x     = (const float*)d_in[0];
    const float* Wih_f = (const float*)d_in[1];
    const float* Whh_f = (const float*)d_in[2];
    const float* bih_f = (const float*)d_in[3];
    const float* bhh_f = (const float*)d_in[4];
    const float* Wih_b = (const float*)d_in[5];
    const float* Whh_b = (const float*)d_in[6];
    const float* bih_b = (const float*)d_in[7];
    const float* bhh_b = (const float*)d_in[8];
    const float* attn_context = (const float*)d_in[9];
    const float* Wattn = (const float*)d_in[10];
    const float* battn = (const float*)d_in[11];
    const float* Wtop  = (const float*)d_in[12];
    const float* btop  = (const float*)d_in[13];
    const float* Wout  = (const float*)d_in[14];
    const float* bout  = (const float*)d_in[15];
    float* outp = (float*)d_out;

    // fixed workspace layout (floats)
    float* ws       = (float*)d_ws;
    float* seqv     = ws;                                   // 19,660,800
    float* hstate   = seqv + (size_t)Bq * Tq * D2;          // 38,400
    float* ctxW     = hstate + (size_t)2 * Bq * Hq;         // 1,800
    float* context  = ctxW + Kq * D2;                       // 230,400
    float* regbuf   = context + (size_t)Bq * Kq * D2;       // 128
    float* normsq   = regbuf + Bq;                          // 768
    float* en       = normsq + Bq * Kq;                     // 393,216
    float* partial  = en + (size_t)Bq * Tq * Kq;            // 1,843,200
    float* gi_chunk = partial + (size_t)Bq * 8 * Kq * D2;   // 115200*TCr
    const size_t fixed_floats = (size_t)(gi_chunk - ws);

    // pick largest TCr in {256,128,64,32} that fits ws_size
    int tcShift = 5;
    for (int sh = 8; sh >= 5; --sh) {
        size_t need = (fixed_floats + (size_t)115200 * (1 << sh)) * 4;
        if (need <= ws_size) { tcShift = sh; break; }
    }
    const int TCr = 1 << tcShift;
    const int NL = Tq / TCr;

    for (int c = 0; c < NL; ++c) {
        const int t0f = c * TCr;
        const int t0b = Tq - TCr * (c + 1);
        gi_gemm<<<dim3(4, Bq * TCr / 128, 2), 256, 0, stream>>>(
            x, Wih_f, bih_f, Wih_b, bih_b, gi_chunk, t0f, t0b, tcShift);
        gru_rec<<<dim3(2 * Bq), 256, 0, stream>>>(
            gi_chunk, Whh_f, bhh_f, Whh_b, bhh_b, hstate, seqv, c, tcShift);
    }

    ctxw_kernel<<<dim3((Kq * D2 + 255) / 256), 256, 0, stream>>>(
        attn_context, Wattn, battn, ctxW);
    ctx_compute<<<dim3(Bq, Kq), 256, 0, stream>>>(seqv, Wattn, ctxW, context, normsq);
    gram_kernel<<<dim3(Bq), 256, 0, stream>>>(context, normsq, regbuf);
    energy_kernel<<<dim3(8, Bq), 256, 0, stream>>>(seqv, context, en);
    softmax_kernel<<<dim3(Bq), 256, 0, stream>>>(en);
    pooledp_kernel<<<dim3(8, Bq), 256, 0, stream>>>(seqv, en, partial);
    final_kernel<<<dim3(Bq), 256, 0, stream>>>(partial, Wtop, btop, Wout, bout, outp);
    reg_final<<<dim3(1), 128, 0, stream>>>(regbuf, outp);
}

// Round 5
// 1356.547 us; speedup vs baseline: 2.5429x; 2.5429x over previous
//
#include <hip/hip_runtime.h>
#include <math.h>

// Problem constants
#define Bq   128
#define Tq   512
#define Iq   300   // input dim
#define Hq   150   // hidden per dir
#define G3   450   // 3*H
#define Kq   6
#define Cq   300
#define D2   300   // 2*H
#define THq  20
#define CLSq 5

// ---------------------------------------------------------------------------
// Kernel 1: gi GEMM, 128x128 block tile, 8x8 per-thread register tile, fp32.
// (unchanged from R3)
// ---------------------------------------------------------------------------
#define BK 16
#define LDP 132   // padded LDS row stride

__global__ __launch_bounds__(256) void gi_gemm(
    const float* __restrict__ x,
    const float* __restrict__ Wf, const float* __restrict__ bf,
    const float* __restrict__ Wb, const float* __restrict__ bb,
    float* __restrict__ gic,     // [2][B][TCr][450]
    int t0f, int t0b, int tcShift)
{
    const int dir = blockIdx.z;
    const float* W    = dir ? Wb : Wf;
    const float* bias = dir ? bb : bf;
    const int t0 = dir ? t0b : t0f;
    const int TCr = 1 << tcShift;
    float* outbase = gic + (size_t)dir * Bq * TCr * G3;

    const int m0 = blockIdx.y * 128;
    const int n0 = blockIdx.x * 128;
    const int tid = threadIdx.x;
    const int tx = tid & 15;    // n-group
    const int ty = tid >> 4;    // m-octet

    __shared__ __align__(16) float As[BK][LDP];
    __shared__ __align__(16) float Bs[BK][LDP];

    const int srow = tid >> 2;      // 0..63 (+64 for q=1)
    const int skq  = tid & 3;

    float acc[8][8];
    #pragma unroll
    for (int i = 0; i < 8; ++i)
        #pragma unroll
        for (int j = 0; j < 8; ++j) acc[i][j] = 0.f;

    for (int k0 = 0; k0 < Iq; k0 += BK) {
        #pragma unroll
        for (int q = 0; q < 2; ++q) {
            const int m = q * 64 + srow;            // local m in tile
            const int r = m0 + m;                   // global row
            const int bb_ = r >> tcShift;
            const int lt = r & (TCr - 1);
            const int kk = k0 + skq * 4;
            float4 av = make_float4(0.f, 0.f, 0.f, 0.f);
            if (kk < Iq)
                av = *(const float4*)(x + ((size_t)bb_ * Tq + t0 + lt) * Iq + kk);
            As[skq*4+0][m] = av.x; As[skq*4+1][m] = av.y;
            As[skq*4+2][m] = av.z; As[skq*4+3][m] = av.w;

            const int n = q * 64 + srow;
            float4 bv = make_float4(0.f, 0.f, 0.f, 0.f);
            if ((n0 + n < G3) && (kk < Iq))
                bv = *(const float4*)(W + (size_t)(n0 + n) * Iq + kk);
            Bs[skq*4+0][n] = bv.x; Bs[skq*4+1][n] = bv.y;
            Bs[skq*4+2][n] = bv.z; Bs[skq*4+3][n] = bv.w;
        }
        __syncthreads();

        #pragma unroll
        for (int k = 0; k < BK; ++k) {
            float4 a0 = *(const float4*)&As[k][ty * 8];
            float4 a1 = *(const float4*)&As[k][ty * 8 + 4];
            float4 b0 = *(const float4*)&Bs[k][tx * 4];
            float4 b1 = *(const float4*)&Bs[k][64 + tx * 4];
            float aa[8] = {a0.x,a0.y,a0.z,a0.w,a1.x,a1.y,a1.z,a1.w};
            float bbv[8] = {b0.x,b0.y,b0.z,b0.w,b1.x,b1.y,b1.z,b1.w};
            #pragma unroll
            for (int i = 0; i < 8; ++i)
                #pragma unroll
                for (int j = 0; j < 8; ++j)
                    acc[i][j] += aa[i] * bbv[j];
        }
        __syncthreads();
    }

    #pragma unroll
    for (int i = 0; i < 8; ++i) {
        const int r = m0 + ty * 8 + i;              // global row
        float* orow = outbase + (size_t)r * G3;
        #pragma unroll
        for (int g = 0; g < 2; ++g) {
            const int n = n0 + g * 64 + tx * 4;
            if (n + 3 < G3) {
                float4 v = make_float4(acc[i][g*4+0] + bias[n],
                                       acc[i][g*4+1] + bias[n+1],
                                       acc[i][g*4+2] + bias[n+2],
                                       acc[i][g*4+3] + bias[n+3]);
                *(float4*)(orow + n) = v;
            } else {
                #pragma unroll
                for (int j = 0; j < 4; ++j)
                    if (n + j < G3) orow[n + j] = acc[i][g*4+j] + bias[n+j];
            }
        }
    }
}

// ---------------------------------------------------------------------------
// Kernel 2: GRU recurrence. 512 threads per (b,dir) block.
// Split-row scheme: thread t = (row-pair j2 = t>>1, half p = t&1) holds
// Whh[2*j2][p*75 .. p*75+74] and Whh[2*j2+1][p*75 ..] = 152 floats total
// (same register footprint R3 proved allocates to AGPRs without spill;
// R4 showed 304 floats/thread spills to scratch). Each lane reads only its
// h-half from LDS: 19 ds_read_b128/wave (even/odd lanes = 2 broadcast
// groups = conflict-free) -> per-step LDS traffic halves vs R3.
// Partials combine with one __shfl_xor(.,1) per row.
// ---------------------------------------------------------------------------
__global__ __launch_bounds__(512, 2) void gru_rec(
    const float* __restrict__ gic,     // [2][B][TCr][450]
    const float* __restrict__ Whh_f, const float* __restrict__ bhh_f,
    const float* __restrict__ Whh_b, const float* __restrict__ bhh_b,
    float* __restrict__ hstate,        // [2][B][150]
    float* __restrict__ seq,           // [B][T][300]
    int chunk, int tcShift)
{
    const int TCr = 1 << tcShift;
    const int bid = blockIdx.x;
    const int dir = bid & 1;
    const int b   = bid >> 1;
    const float* Whh = dir ? Whh_b : Whh_f;
    const float* bhh = dir ? bhh_b : bhh_f;
    const int tid = threadIdx.x;
    const int j2  = tid >> 1;          // row pair index (valid < 225)
    const int p   = tid & 1;           // h-half
    const bool gact = (tid < 450);     // gemv role active

    __shared__ __align__(16) float stage[64 * 150];  // 37.5 KB W-staging
    __shared__ __align__(16) float4 hbuf4[38];       // h in halves padded to 2*76
    __shared__ float gh_s[456];
    __shared__ float gi_s[456];
    float* hbuf = (float*)hbuf4;

    float w0[76], w1[76];

    // --- load weight slices via coalesced LDS staging (8 chunks of 64 rows)
    // thread's rows 2*j2, 2*j2+1 are always in the same 64-row chunk (j2>>5).
    for (int c = 0; c < 8; ++c) {
        const int r0 = c * 64;
        const int nrows = (r0 + 64 <= G3) ? 64 : (G3 - r0);
        const int nel = nrows * 150;
        __syncthreads();
        for (int idx = tid * 4; idx < nel; idx += 512 * 4)
            *(float4*)&stage[idx] = *(const float4*)(Whh + (size_t)r0 * 150 + idx);
        __syncthreads();
        if (gact && (j2 >> 5) == c) {
            const int rl = 2 * j2 - r0;             // 0..62 even
            #pragma unroll
            for (int m = 0; m < 75; ++m) {
                w0[m] = stage[rl * 150 + p * 75 + m];
                w1[m] = stage[(rl + 1) * 150 + p * 75 + m];
            }
        }
    }
    w0[75] = 0.f; w1[75] = 0.f;
    const float bh0 = (gact && p == 0) ? bhh[2 * j2]     : 0.f;
    const float bh1 = (gact && p == 0) ? bhh[2 * j2 + 1] : 0.f;

    float* hs = hstate + (size_t)(dir * Bq + b) * Hq;
    // h LDS layout: slot = half*76 + m  (m<75 -> h[half*75+m], m==75 -> 0 pad)
    if (tid < 152) {
        const int pp = tid / 76, mm = tid % 76;
        hbuf[tid] = (mm < 75 && chunk > 0) ? hs[pp * 75 + mm] : 0.f;
    }
    __syncthreads();

    const float* gib = gic + (size_t)(dir * Bq + b) * TCr * G3;
    const int t0 = dir ? (Tq - TCr * (chunk + 1)) : (chunk * TCr);
    float* seqb = seq + (size_t)b * Tq * D2 + dir * Hq;

    int lt = dir ? (TCr - 1) : 0;
    float gval = gact ? gib[(size_t)lt * G3 + tid] : 0.f;   // gi for row `tid`

    for (int s = 0; s < TCr; ++s) {
        const int ltn = dir ? (TCr - 2 - s) : (s + 1);
        float gnext = 0.f;
        if (s + 1 < TCr && gact)
            gnext = gib[(size_t)ltn * G3 + tid];

        if (gact) {
            float acc0 = 0.f, acc1 = 0.f;
            const float4* hh = hbuf4 + p * 19;      // this lane's h-half
            #pragma unroll
            for (int q = 0; q < 19; ++q) {
                float4 hv = hh[q];                  // 2-group broadcast read
                acc0 += hv.x * w0[q*4+0] + hv.y * w0[q*4+1]
                      + hv.z * w0[q*4+2] + hv.w * w0[q*4+3];
                acc1 += hv.x * w1[q*4+0] + hv.y * w1[q*4+1]
                      + hv.z * w1[q*4+2] + hv.w * w1[q*4+3];
            }
            const float o0 = __shfl_xor(acc0, 1);   // partner half, same rows
            const float o1 = __shfl_xor(acc1, 1);
            if (p == 0)
                *(float2*)&gh_s[2 * j2] = make_float2(acc0 + o0 + bh0,
                                                      acc1 + o1 + bh1);
            gi_s[tid] = gval;                       // row `tid` staging
        }
        __syncthreads();

        if (tid < Hq) {
            const float r = 1.f / (1.f + __expf(-(gi_s[tid]       + gh_s[tid])));
            const float z = 1.f / (1.f + __expf(-(gi_s[150 + tid] + gh_s[150 + tid])));
            const float nv = tanhf(gi_s[300 + tid] + r * gh_s[300 + tid]);
            const int slot = (tid / 75) * 76 + (tid % 75);
            const float hn = (1.f - z) * nv + z * hbuf[slot];
            hbuf[slot] = hn;
            seqb[(size_t)(t0 + lt) * D2 + tid] = hn;
        }
        __syncthreads();

        gval = gnext;
        lt = ltn;
    }

    if (tid < Hq) hs[tid] = hbuf[(tid / 75) * 76 + (tid % 75)];
}

// ---------------------------------------------------------------------------
// Kernel 3a: ctxW[k][d] = battn[k][d] + sum_c attn_context[k][c]*Wattn[k][c][d]
// ---------------------------------------------------------------------------
__global__ void ctxw_kernel(
    const float* __restrict__ attn_context,
    const float* __restrict__ Wattn,
    const float* __restrict__ battn,
    float* __restrict__ ctxW)
{
    const int o = blockIdx.x * 256 + threadIdx.x;
    if (o >= Kq * D2) return;
    const int k = o / D2, d = o % D2;
    float acc = battn[o];
    const float* Wp = Wattn + ((size_t)k * (Cq + D2)) * D2 + d;
    for (int c = 0; c < Cq; ++c)
        acc += attn_context[k * Cq + c] * Wp[(size_t)c * D2];
    ctxW[o] = acc;
}

// ---------------------------------------------------------------------------
// Kernel 3b: context[b][k][:] = tanh(ctxW[k] + hidden[b] @ Wattn[k,300:,:])
// ---------------------------------------------------------------------------
__global__ __launch_bounds__(256) void ctx_compute(
    const float* __restrict__ seq,
    const float* __restrict__ Wattn,
    const float* __restrict__ ctxW,
    float* __restrict__ context,      // [B][6][300]
    float* __restrict__ normsq)       // [B][6]
{
    const int b = blockIdx.x;
    const int k = blockIdx.y;
    const int tid = threadIdx.x;
    const int lane = tid & 63, wv = tid >> 6;

    __shared__ float hb[304];
    __shared__ float red[4];

    for (int i = tid; i < D2; i += 256)
        hb[i] = (i < Hq) ? seq[((size_t)b * Tq + (Tq - 1)) * D2 + i]
                         : seq[(size_t)b * Tq * D2 + i];
    __syncthreads();

    float ssq = 0.f;
    for (int d = tid; d < D2; d += 256) {
        float acc = ctxW[k * D2 + d];
        const float* Wp = Wattn + ((size_t)k * (Cq + D2) + Cq) * D2 + d;
        for (int jj = 0; jj < D2; ++jj)
            acc += hb[jj] * Wp[(size_t)jj * D2];
        const float c = tanhf(acc);
        context[((size_t)b * Kq + k) * D2 + d] = c;
        ssq += c * c;
    }
    for (int off = 32; off > 0; off >>= 1) ssq += __shfl_xor(ssq, off, 64);
    if (lane == 0) red[wv] = ssq;
    __syncthreads();
    if (tid == 0) normsq[b * Kq + k] = red[0] + red[1] + red[2] + red[3];
}

// ---------------------------------------------------------------------------
// Kernel 3c: gram regularizer per b
// ---------------------------------------------------------------------------
__global__ __launch_bounds__(256) void gram_kernel(
    const float* __restrict__ context,
    const float* __restrict__ normsq,
    float* __restrict__ regbuf)
{
    const int b = blockIdx.x;
    const int tid = threadIdx.x;
    __shared__ float ctx[Kq * D2];
    __shared__ float Gm[36];

    for (int o = tid; o < Kq * D2; o += 256)
        ctx[o] = context[(size_t)b * Kq * D2 + o];
    __syncthreads();

    if (tid < 36) {
        const int k = tid / 6, jj = tid % 6;
        float g = 0.f;
        for (int d = 0; d < D2; ++d)
            g += ctx[k * D2 + d] * ctx[jj * D2 + d];
        const float nk = fmaxf(sqrtf(normsq[b * Kq + k]), 1e-12f);
        const float nj = fmaxf(sqrtf(normsq[b * Kq + jj]), 1e-12f);
        g /= (nk * nj);
        const float diff = g - ((k == jj) ? 1.f : 0.f);
        Gm[tid] = diff * diff;
    }
    __syncthreads();
    if (tid == 0) {
        float s = 0.f;
        for (int i = 0; i < 36; ++i) s += Gm[i];
        regbuf[b] = sqrtf(s);
    }
}

// ---------------------------------------------------------------------------
// Kernel 4a: energy[b][t][k] = seq[b][t] . context[b][k]   grid (8, B)
// ---------------------------------------------------------------------------
__global__ __launch_bounds__(256) void energy_kernel(
    const float* __restrict__ seq,
    const float* __restrict__ context,
    float* __restrict__ en)           // [B][512][6]
{
    const int tc = blockIdx.x;
    const int b  = blockIdx.y;
    const int tid = threadIdx.x;
    const int lane = tid & 63, wv = tid >> 6;

    __shared__ float ctx[Kq * D2];
    for (int o = tid; o < Kq * D2; o += 256)
        ctx[o] = context[(size_t)b * Kq * D2 + o];
    __syncthreads();

    const float* seqb = seq + (size_t)b * Tq * D2;
    for (int s = 0; s < 16; ++s) {
        const int tt = tc * 64 + s * 4 + wv;
        float acc[Kq] = {0.f,0.f,0.f,0.f,0.f,0.f};
        for (int d = lane; d < D2; d += 64) {
            const float sv = seqb[(size_t)tt * D2 + d];
            #pragma unroll
            for (int k = 0; k < Kq; ++k) acc[k] += sv * ctx[k * D2 + d];
        }
        #pragma unroll
        for (int k = 0; k < Kq; ++k) {
            float v = acc[k];
            for (int off = 32; off > 0; off >>= 1) v += __shfl_xor(v, off, 64);
            if (lane == 0) en[((size_t)b * Tq + tt) * Kq + k] = v;
        }
    }
}

// ---------------------------------------------------------------------------
// Kernel 4b: softmax over t per (b,k), in-place on en.  grid (B)
// ---------------------------------------------------------------------------
__global__ __launch_bounds__(256) void softmax_kernel(float* __restrict__ en)
{
    const int b = blockIdx.x;
    const int tid = threadIdx.x;
    const int lane = tid & 63, wv = tid >> 6;
    __shared__ float es[Tq * Kq];
    __shared__ float red[8];

    for (int o = tid; o < Tq * Kq; o += 256)
        es[o] = en[(size_t)b * Tq * Kq + o];
    __syncthreads();

    for (int k = 0; k < Kq; ++k) {
        float m = -1e30f;
        for (int tt = tid; tt < Tq; tt += 256) m = fmaxf(m, es[tt * Kq + k]);
        for (int off = 32; off > 0; off >>= 1) m = fmaxf(m, __shfl_xor(m, off, 64));
        if (lane == 0) red[wv] = m;
        __syncthreads();
        m = fmaxf(fmaxf(red[0], red[1]), fmaxf(red[2], red[3]));
        float ssum = 0.f;
        for (int tt = tid; tt < Tq; tt += 256) {
            const float e = __expf(es[tt * Kq + k] - m);
            es[tt * Kq + k] = e;
            ssum += e;
        }
        for (int off = 32; off > 0; off >>= 1) ssum += __shfl_xor(ssum, off, 64);
        if (lane == 0) red[4 + wv] = ssum;
        __syncthreads();
        const float inv = 1.f / (red[4] + red[5] + red[6] + red[7]);
        for (int tt = tid; tt < Tq; tt += 256) es[tt * Kq + k] *= inv;
        __syncthreads();
    }

    for (int o = tid; o < Tq * Kq; o += 256)
        en[(size_t)b * Tq * Kq + o] = es[o];
}

// ---------------------------------------------------------------------------
// Kernel 4c: pooled partials over 64-t chunks.  grid (8, B)
// ---------------------------------------------------------------------------
__global__ __launch_bounds__(256) void pooledp_kernel(
    const float* __restrict__ seq,
    const float* __restrict__ en,     // probs now
    float* __restrict__ partial)      // [B*8][1800]
{
    const int tc = blockIdx.x;
    const int b  = blockIdx.y;
    const int tid = threadIdx.x;
    const int lane = tid & 63, wv = tid >> 6;

    __shared__ float pr[64 * Kq];
    __shared__ float part[4][Kq * D2];   // 28.8 KB

    if (tid < 64 * Kq / 2) {
        pr[tid]       = en[((size_t)b * Tq + tc * 64) * Kq + tid];
        pr[tid + 192] = en[((size_t)b * Tq + tc * 64) * Kq + tid + 192];
    }
    __syncthreads();

    const float* seqb = seq + (size_t)b * Tq * D2;

    float pp[Kq][5];
    #pragma unroll
    for (int k = 0; k < Kq; ++k)
        #pragma unroll
        for (int q = 0; q < 5; ++q) pp[k][q] = 0.f;

    for (int s = 0; s < 16; ++s) {
        const int tl = s * 4 + wv;
        const int tt = tc * 64 + tl;
        float prr[Kq];
        #pragma unroll
        for (int k = 0; k < Kq; ++k) prr[k] = pr[tl * Kq + k];
        #pragma unroll
        for (int q = 0; q < 5; ++q) {
            const int d = lane + q * 64;
            const float sv = (d < D2) ? seqb[(size_t)tt * D2 + d] : 0.f;
            #pragma unroll
            for (int k = 0; k < Kq; ++k) pp[k][q] += prr[k] * sv;
        }
    }
    #pragma unroll
    for (int k = 0; k < Kq; ++k)
        #pragma unroll
        for (int q = 0; q < 5; ++q) {
            const int d = lane + q * 64;
            if (d < D2) part[wv][k * D2 + d] = pp[k][q];
        }
    __syncthreads();
    float* op = partial + ((size_t)b * 8 + tc) * (Kq * D2);
    for (int o = tid; o < Kq * D2; o += 256)
        op[o] = part[0][o] + part[1][o] + part[2][o] + part[3][o];
}

// ---------------------------------------------------------------------------
// Kernel 4d: final: pooled reduce -> topic -> logits -> softmax.  grid (B)
// ---------------------------------------------------------------------------
__global__ __launch_bounds__(256) void final_kernel(
    const float* __restrict__ partial,
    const float* __restrict__ Wtop,
    const float* __restrict__ btop,
    const float* __restrict__ Wout,
    const float* __restrict__ bout,
    float* __restrict__ outp)
{
    const int b = blockIdx.x;
    const int tid = threadIdx.x;
    __shared__ float pooled[Kq * D2];
    __shared__ float feats[Kq * THq];
    __shared__ float lsm[8];

    for (int o = tid; o < Kq * D2; o += 256) {
        float s = 0.f;
        #pragma unroll
        for (int c = 0; c < 8; ++c)
            s += partial[((size_t)b * 8 + c) * (Kq * D2) + o];
        pooled[o] = s;
    }
    __syncthreads();

    if (tid < Kq * THq) {
        const int k = tid / THq, hh = tid % THq;
        float acc = btop[tid];
        const float* wp = Wtop + (size_t)k * D2 * THq + hh;
        for (int d = 0; d < D2; ++d)
            acc += pooled[k * D2 + d] * wp[(size_t)d * THq];
        feats[tid] = fmaxf(acc, 0.f);
    }
    __syncthreads();

    if (tid < CLSq) {
        float acc = bout[tid];
        for (int f = 0; f < Kq * THq; ++f)
            acc += feats[f] * Wout[f * CLSq + tid];
        lsm[tid] = acc;
    }
    __syncthreads();
    if (tid < CLSq) {
        float m = lsm[0];
        for (int c = 1; c < CLSq; ++c) m = fmaxf(m, lsm[c]);
        float s = 0.f;
        for (int c = 0; c < CLSq; ++c) s += __expf(lsm[c] - m);
        outp[(size_t)b * CLSq + tid] = __expf(lsm[tid] - m) / s;
    }
}

// ---------------------------------------------------------------------------
// Kernel 5: reg = mean_b regbuf[b]  -> d_out[640]
// ---------------------------------------------------------------------------
__global__ void reg_final(const float* __restrict__ regbuf, float* __restrict__ outp)
{
    const int tid = threadIdx.x;   // 128 threads
    float v = regbuf[tid];
    for (int off = 32; off > 0; off >>= 1) v += __shfl_xor(v, off, 64);
    __shared__ float r2[2];
    if ((tid & 63) == 0) r2[tid >> 6] = v;
    __syncthreads();
    if (tid == 0) outp[Bq * CLSq] = (r2[0] + r2[1]) * (1.f / (float)Bq);
}

// ---------------------------------------------------------------------------
extern "C" void kernel_launch(void* const* d_in, const int* in_sizes, int n_in,
                              void* d_out, int out_size, void* d_ws, size_t ws_size,
                              hipStream_t stream)
{
    const float* x     = (const float*)d_in[0];
    const float* Wih_f = (const float*)d_in[1];
    const float* Whh_f = (const float*)d_in[2];
    const float* bih_f = (const float*)d_in[3];
    const float* bhh_f = (const float*)d_in[4];
    const float* Wih_b = (const float*)d_in[5];
    const float* Whh_b = (const float*)d_in[6];
    const float* bih_b = (const float*)d_in[7];
    const float* bhh_b = (const float*)d_in[8];
    const float* attn_context = (const float*)d_in[9];
    const float* Wattn = (const float*)d_in[10];
    const float* battn = (const float*)d_in[11];
    const float* Wtop  = (const float*)d_in[12];
    const float* btop  = (const float*)d_in[13];
    const float* Wout  = (const float*)d_in[14];
    const float* bout  = (const float*)d_in[15];
    float* outp = (float*)d_out;

    // fixed workspace layout (floats)
    float* ws       = (float*)d_ws;
    float* seqv     = ws;                                   // 19,660,800
    float* hstate   = seqv + (size_t)Bq * Tq * D2;          // 38,400
    float* ctxW     = hstate + (size_t)2 * Bq * Hq;         // 1,800
    float* context  = ctxW + Kq * D2;                       // 230,400
    float* regbuf   = context + (size_t)Bq * Kq * D2;       // 128
    float* normsq   = regbuf + Bq;                          // 768
    float* en       = normsq + Bq * Kq;                     // 393,216
    float* partial  = en + (size_t)Bq * Tq * Kq;            // 1,843,200
    float* gi_chunk = partial + (size_t)Bq * 8 * Kq * D2;   // 115200*TCr
    const size_t fixed_floats = (size_t)(gi_chunk - ws);

    // pick largest TCr in {256,128,64,32} that fits ws_size
    int tcShift = 5;
    for (int sh = 8; sh >= 5; --sh) {
        size_t need = (fixed_floats + (size_t)115200 * (1 << sh)) * 4;
        if (need <= ws_size) { tcShift = sh; break; }
    }
    const int TCr = 1 << tcShift;
    const int NL = Tq / TCr;

    for (int c = 0; c < NL; ++c) {
        const int t0f = c * TCr;
        const int t0b = Tq - TCr * (c + 1);
        gi_gemm<<<dim3(4, Bq * TCr / 128, 2), 256, 0, stream>>>(
            x, Wih_f, bih_f, Wih_b, bih_b, gi_chunk, t0f, t0b, tcShift);
        gru_rec<<<dim3(2 * Bq), 512, 0, stream>>>(
            gi_chunk, Whh_f, bhh_f, Whh_b, bhh_b, hstate, seqv, c, tcShift);
    }

    ctxw_kernel<<<dim3((Kq * D2 + 255) / 256), 256, 0, stream>>>(
        attn_context, Wattn, battn, ctxW);
    ctx_compute<<<dim3(Bq, Kq), 256, 0, stream>>>(seqv, Wattn, ctxW, context, normsq);
    gram_kernel<<<dim3(Bq), 256, 0, stream>>>(context, normsq, regbuf);
    energy_kernel<<<dim3(8, Bq), 256, 0, stream>>>(seqv, context, en);
    softmax_kernel<<<dim3(Bq), 256, 0, stream>>>(en);
    pooledp_kernel<<<dim3(8, Bq), 256, 0, stream>>>(seqv, en, partial);
    final_kernel<<<dim3(Bq), 256, 0, stream>>>(partial, Wtop, btop, Wout, bout, outp);
    reg_final<<<dim3(1), 128, 0, stream>>>(regbuf, outp);
}

// Round 6
// 1064.990 us; speedup vs baseline: 3.2390x; 1.2738x over previous
//
#include <hip/hip_runtime.h>
#include <hip/hip_bf16.h>
#include <math.h>

// Problem constants
#define Bq   128
#define Tq   512
#define Iq   300   // input dim
#define Hq   150   // hidden per dir
#define G3   450   // 3*H
#define Kq   6
#define Cq   300
#define D2   300   // 2*H
#define THq  20
#define CLSq 5

typedef __attribute__((ext_vector_type(8))) short short8;     // 8 bf16 (4 VGPR) MFMA A/B frag
typedef __attribute__((ext_vector_type(4))) float floatx4;    // MFMA C/D frag

// ---------------------------------------------------------------------------
// Kernel 0: fp32 -> bf16 cast (RNE). n4 = n/4.
// ---------------------------------------------------------------------------
__global__ __launch_bounds__(256) void cast_bf16_kernel(
    const float* __restrict__ in, __hip_bfloat16* __restrict__ out, int n4)
{
    const int i = blockIdx.x * 256 + threadIdx.x;
    if (i < n4) {
        float4 v = *(const float4*)(in + 4 * (size_t)i);
        out[4 * (size_t)i + 0] = __float2bfloat16(v.x);
        out[4 * (size_t)i + 1] = __float2bfloat16(v.y);
        out[4 * (size_t)i + 2] = __float2bfloat16(v.z);
        out[4 * (size_t)i + 3] = __float2bfloat16(v.w);
    }
}

// ---------------------------------------------------------------------------
// Kernel 1: gi GEMM via bf16 MFMA 16x16x32 (verified gfx950 layouts:
// A/B frag [r=lane&15][k=(lane>>4)*8+j], C/D col=lane&15,row=(lane>>4)*4+reg).
// Block 256 thr = 4 waves (2x2), wave tile 64x64, block tile 128x128, K
// padded to 320 with zeros. LDS rows stride 40 bf16 (80 B: 16B-aligned for
// ds_read_b128, 2-way-broadcast bank pattern = free per m136).
// ---------------------------------------------------------------------------
#define LB 40

__global__ __launch_bounds__(256) void gi_gemm_mfma(
    const __hip_bfloat16* __restrict__ xb,    // [B][T][300] bf16
    const __hip_bfloat16* __restrict__ Wbf,   // [2][450][300] bf16
    const float* __restrict__ bf_, const float* __restrict__ bb_,
    float* __restrict__ gic, int t0f, int t0b, int tcShift)
{
    const int dir = blockIdx.z;
    const unsigned short* W = (const unsigned short*)(Wbf + (size_t)dir * G3 * Iq);
    const unsigned short* X = (const unsigned short*)xb;
    const float* bias = dir ? bb_ : bf_;
    const int t0 = dir ? t0b : t0f;
    const int TCr = 1 << tcShift;
    float* outb = gic + (size_t)dir * Bq * TCr * G3;

    const int m0 = blockIdx.y * 128;
    const int n0 = blockIdx.x * 128;
    const int tid  = threadIdx.x;
    const int wv   = tid >> 6, lane = tid & 63;
    const int wm   = wv & 1,  wn   = wv >> 1;
    const int quad = lane >> 4, mr = lane & 15;

    __shared__ __align__(16) unsigned short Ab[128 * LB];
    __shared__ __align__(16) unsigned short Bb[128 * LB];

    floatx4 acc[4][4];
    #pragma unroll
    for (int i = 0; i < 4; ++i)
        #pragma unroll
        for (int j = 0; j < 4; ++j)
            acc[i][j] = (floatx4){0.f, 0.f, 0.f, 0.f};

    for (int k0 = 0; k0 < 320; k0 += 32) {
        __syncthreads();
        #pragma unroll
        for (int i = 0; i < 4; ++i) {
            const int g = tid + 256 * i;         // 0..1023
            const int row = g >> 3, kq = g & 7;  // 4-bf16 granule
            const int k = k0 + kq * 4;
            // A granule
            const int r = m0 + row;
            const int bb2 = r >> tcShift, lt = r & (TCr - 1);
            ushort4 av = make_ushort4(0, 0, 0, 0);
            if (k < Iq)
                av = *(const ushort4*)(X + ((size_t)bb2 * Tq + t0 + lt) * Iq + k);
            *(ushort4*)&Ab[row * LB + kq * 4] = av;
            // B granule
            const int n = n0 + row;
            ushort4 bv = make_ushort4(0, 0, 0, 0);
            if (n < G3 && k < Iq)
                bv = *(const ushort4*)(W + (size_t)n * Iq + k);
            *(ushort4*)&Bb[row * LB + kq * 4] = bv;
        }
        __syncthreads();

        short8 af[4], bfr[4];
        #pragma unroll
        for (int i = 0; i < 4; ++i)
            af[i] = *(const short8*)&Ab[(wm * 64 + i * 16 + mr) * LB + quad * 8];
        #pragma unroll
        for (int j = 0; j < 4; ++j)
            bfr[j] = *(const short8*)&Bb[(wn * 64 + j * 16 + mr) * LB + quad * 8];
        #pragma unroll
        for (int i = 0; i < 4; ++i)
            #pragma unroll
            for (int j = 0; j < 4; ++j)
                acc[i][j] = __builtin_amdgcn_mfma_f32_16x16x32_bf16(
                    af[i], bfr[j], acc[i][j], 0, 0, 0);
    }

    #pragma unroll
    for (int j = 0; j < 4; ++j) {
        const int gn = n0 + wn * 64 + j * 16 + mr;
        if (gn >= G3) continue;
        const float bv = bias[gn];
        #pragma unroll
        for (int i = 0; i < 4; ++i) {
            const int mbase = m0 + wm * 64 + i * 16 + quad * 4;
            #pragma unroll
            for (int rg = 0; rg < 4; ++rg)
                outb[(size_t)(mbase + rg) * G3 + gn] = acc[i][j][rg] + bv;
        }
    }
}

// ---------------------------------------------------------------------------
// Kernel 2: GRU recurrence (split-row scheme from R5: thread=(j2,half) holds
// 2x76 weight floats; h-half broadcast reads). R6 change: h outputs go to an
// LDS history (reusing stage[]) and flush to global once per 64 steps, so
// per-step __syncthreads no longer drains a pending global store (vmcnt(0)
// stall was the ~1200 cyc/step gap in the R5 model). Accumulator chains
// split 2-way for ILP.
// ---------------------------------------------------------------------------
__global__ __launch_bounds__(512, 2) void gru_rec(
    const float* __restrict__ gic,     // [2][B][TCr][450]
    const float* __restrict__ Whh_f, const float* __restrict__ bhh_f,
    const float* __restrict__ Whh_b, const float* __restrict__ bhh_b,
    float* __restrict__ hstate,        // [2][B][150]
    float* __restrict__ seq,           // [B][T][300]
    int chunk, int tcShift)
{
    const int TCr = 1 << tcShift;
    const int bid = blockIdx.x;
    const int dir = bid & 1;
    const int b   = bid >> 1;
    const float* Whh = dir ? Whh_b : Whh_f;
    const float* bhh = dir ? bhh_b : bhh_f;
    const int tid = threadIdx.x;
    const int j2  = tid >> 1;          // row pair index (valid < 225)
    const int p   = tid & 1;           // h-half
    const bool gact = (tid < 450);

    __shared__ __align__(16) float stage[64 * 150];  // W-staging, then h history
    __shared__ __align__(16) float4 hbuf4[38];       // h halves padded to 2*76
    __shared__ float gh_s[456];
    __shared__ float gi_s[456];
    float* hbuf = (float*)hbuf4;

    float w0[76], w1[76];

    for (int c = 0; c < 8; ++c) {
        const int r0 = c * 64;
        const int nrows = (r0 + 64 <= G3) ? 64 : (G3 - r0);
        const int nel = nrows * 150;
        __syncthreads();
        for (int idx = tid * 4; idx < nel; idx += 512 * 4)
            *(float4*)&stage[idx] = *(const float4*)(Whh + (size_t)r0 * 150 + idx);
        __syncthreads();
        if (gact && (j2 >> 5) == c) {
            const int rl = 2 * j2 - r0;
            #pragma unroll
            for (int m = 0; m < 75; ++m) {
                w0[m] = stage[rl * 150 + p * 75 + m];
                w1[m] = stage[(rl + 1) * 150 + p * 75 + m];
            }
        }
    }
    w0[75] = 0.f; w1[75] = 0.f;
    const float bh0 = (gact && p == 0) ? bhh[2 * j2]     : 0.f;
    const float bh1 = (gact && p == 0) ? bhh[2 * j2 + 1] : 0.f;

    float* hs = hstate + (size_t)(dir * Bq + b) * Hq;
    if (tid < 152) {
        const int pp = tid / 76, mm = tid % 76;
        hbuf[tid] = (mm < 75 && chunk > 0) ? hs[pp * 75 + mm] : 0.f;
    }
    __syncthreads();

    const float* gib = gic + (size_t)(dir * Bq + b) * TCr * G3;
    const int t0 = dir ? (Tq - TCr * (chunk + 1)) : (chunk * TCr);
    float* seqb = seq + (size_t)b * Tq * D2 + dir * Hq;

    int lt = dir ? (TCr - 1) : 0;
    float gval = gact ? gib[(size_t)lt * G3 + tid] : 0.f;

    for (int s = 0; s < TCr; ++s) {
        const int ltn = dir ? (TCr - 2 - s) : (s + 1);
        float gnext = 0.f;
        if (s + 1 < TCr && gact)
            gnext = gib[(size_t)ltn * G3 + tid];

        if (gact) {
            float a0a = 0.f, a0b = 0.f, a1a = 0.f, a1b = 0.f;
            const float4* hh = hbuf4 + p * 19;
            #pragma unroll
            for (int q = 0; q < 19; q += 2) {
                float4 hv = hh[q];
                a0a += hv.x * w0[q*4+0] + hv.y * w0[q*4+1]
                     + hv.z * w0[q*4+2] + hv.w * w0[q*4+3];
                a1a += hv.x * w1[q*4+0] + hv.y * w1[q*4+1]
                     + hv.z * w1[q*4+2] + hv.w * w1[q*4+3];
            }
            #pragma unroll
            for (int q = 1; q < 19; q += 2) {
                float4 hv = hh[q];
                a0b += hv.x * w0[q*4+0] + hv.y * w0[q*4+1]
                     + hv.z * w0[q*4+2] + hv.w * w0[q*4+3];
                a1b += hv.x * w1[q*4+0] + hv.y * w1[q*4+1]
                     + hv.z * w1[q*4+2] + hv.w * w1[q*4+3];
            }
            float acc0 = a0a + a0b, acc1 = a1a + a1b;
            const float o0 = __shfl_xor(acc0, 1);
            const float o1 = __shfl_xor(acc1, 1);
            if (p == 0)
                *(float2*)&gh_s[2 * j2] = make_float2(acc0 + o0 + bh0,
                                                      acc1 + o1 + bh1);
            gi_s[tid] = gval;
        }
        __syncthreads();   // drains gi prefetch (issued ~gemv-length ago) + LDS

        if (tid < Hq) {
            const float r = 1.f / (1.f + __expf(-(gi_s[tid]       + gh_s[tid])));
            const float z = 1.f / (1.f + __expf(-(gi_s[150 + tid] + gh_s[150 + tid])));
            const float nv = tanhf(gi_s[300 + tid] + r * gh_s[300 + tid]);
            const int slot = (tid / 75) * 76 + (tid % 75);
            const float hn = (1.f - z) * nv + z * hbuf[slot];
            hbuf[slot] = hn;
            stage[(s & 63) * 150 + tid] = hn;   // LDS history, no global store
        }
        __syncthreads();   // LDS-only: no vmem drain on critical path

        // periodic cooperative flush of the h history (global stores drain
        // lazily at the NEXT step's first barrier, amortized over 64 steps)
        if ((s & 63) == 63 || s == TCr - 1) {
            const int sf0 = s & ~63;
            const int nf2 = (s - sf0 + 1) * 75;        // float2 count
            for (int idx = tid; idx < nf2; idx += 512) {
                const int rrow = idx / 75, cc = idx % 75;
                const int ss = sf0 + rrow;
                const int ltw = dir ? (TCr - 1 - ss) : ss;
                *(float2*)(seqb + (size_t)(t0 + ltw) * D2 + 2 * cc) =
                    *(const float2*)&stage[rrow * 150 + 2 * cc];
            }
        }

        gval = gnext;
        lt = ltn;
    }

    if (tid < Hq) hs[tid] = hbuf[(tid / 75) * 76 + (tid % 75)];
}

// ---------------------------------------------------------------------------
// Kernel 3a: ctxW[k][d] = battn[k][d] + sum_c attn_context[k][c]*Wattn[k][c][d]
// ---------------------------------------------------------------------------
__global__ void ctxw_kernel(
    const float* __restrict__ attn_context,
    const float* __restrict__ Wattn,
    const float* __restrict__ battn,
    float* __restrict__ ctxW)
{
    const int o = blockIdx.x * 256 + threadIdx.x;
    if (o >= Kq * D2) return;
    const int k = o / D2, d = o % D2;
    float acc = battn[o];
    const float* Wp = Wattn + ((size_t)k * (Cq + D2)) * D2 + d;
    for (int c = 0; c < Cq; ++c)
        acc += attn_context[k * Cq + c] * Wp[(size_t)c * D2];
    ctxW[o] = acc;
}

// ---------------------------------------------------------------------------
// Kernel 3b: context[b][k][:] = tanh(ctxW[k] + hidden[b] @ Wattn[k,300:,:])
// ---------------------------------------------------------------------------
__global__ __launch_bounds__(256) void ctx_compute(
    const float* __restrict__ seq,
    const float* __restrict__ Wattn,
    const float* __restrict__ ctxW,
    float* __restrict__ context,      // [B][6][300]
    float* __restrict__ normsq)       // [B][6]
{
    const int b = blockIdx.x;
    const int k = blockIdx.y;
    const int tid = threadIdx.x;
    const int lane = tid & 63, wv = tid >> 6;

    __shared__ float hb[304];
    __shared__ float red[4];

    for (int i = tid; i < D2; i += 256)
        hb[i] = (i < Hq) ? seq[((size_t)b * Tq + (Tq - 1)) * D2 + i]
                         : seq[(size_t)b * Tq * D2 + i];
    __syncthreads();

    float ssq = 0.f;
    for (int d = tid; d < D2; d += 256) {
        float acc = ctxW[k * D2 + d];
        const float* Wp = Wattn + ((size_t)k * (Cq + D2) + Cq) * D2 + d;
        for (int jj = 0; jj < D2; ++jj)
            acc += hb[jj] * Wp[(size_t)jj * D2];
        const float c = tanhf(acc);
        context[((size_t)b * Kq + k) * D2 + d] = c;
        ssq += c * c;
    }
    for (int off = 32; off > 0; off >>= 1) ssq += __shfl_xor(ssq, off, 64);
    if (lane == 0) red[wv] = ssq;
    __syncthreads();
    if (tid == 0) normsq[b * Kq + k] = red[0] + red[1] + red[2] + red[3];
}

// ---------------------------------------------------------------------------
// Kernel 3c: gram regularizer per b
// ---------------------------------------------------------------------------
__global__ __launch_bounds__(256) void gram_kernel(
    const float* __restrict__ context,
    const float* __restrict__ normsq,
    float* __restrict__ regbuf)
{
    const int b = blockIdx.x;
    const int tid = threadIdx.x;
    __shared__ float ctx[Kq * D2];
    __shared__ float Gm[36];

    for (int o = tid; o < Kq * D2; o += 256)
        ctx[o] = context[(size_t)b * Kq * D2 + o];
    __syncthreads();

    if (tid < 36) {
        const int k = tid / 6, jj = tid % 6;
        float g = 0.f;
        for (int d = 0; d < D2; ++d)
            g += ctx[k * D2 + d] * ctx[jj * D2 + d];
        const float nk = fmaxf(sqrtf(normsq[b * Kq + k]), 1e-12f);
        const float nj = fmaxf(sqrtf(normsq[b * Kq + jj]), 1e-12f);
        g /= (nk * nj);
        const float diff = g - ((k == jj) ? 1.f : 0.f);
        Gm[tid] = diff * diff;
    }
    __syncthreads();
    if (tid == 0) {
        float s = 0.f;
        for (int i = 0; i < 36; ++i) s += Gm[i];
        regbuf[b] = sqrtf(s);
    }
}

// ---------------------------------------------------------------------------
// Kernel 4a: energy[b][t][k] = seq[b][t] . context[b][k]   grid (8, B)
// ---------------------------------------------------------------------------
__global__ __launch_bounds__(256) void energy_kernel(
    const float* __restrict__ seq,
    const float* __restrict__ context,
    float* __restrict__ en)           // [B][512][6]
{
    const int tc = blockIdx.x;
    const int b  = blockIdx.y;
    const int tid = threadIdx.x;
    const int lane = tid & 63, wv = tid >> 6;

    __shared__ float ctx[Kq * D2];
    for (int o = tid; o < Kq * D2; o += 256)
        ctx[o] = context[(size_t)b * Kq * D2 + o];
    __syncthreads();

    const float* seqb = seq + (size_t)b * Tq * D2;
    for (int s = 0; s < 16; ++s) {
        const int tt = tc * 64 + s * 4 + wv;
        float acc[Kq] = {0.f,0.f,0.f,0.f,0.f,0.f};
        for (int d = lane; d < D2; d += 64) {
            const float sv = seqb[(size_t)tt * D2 + d];
            #pragma unroll
            for (int k = 0; k < Kq; ++k) acc[k] += sv * ctx[k * D2 + d];
        }
        #pragma unroll
        for (int k = 0; k < Kq; ++k) {
            float v = acc[k];
            for (int off = 32; off > 0; off >>= 1) v += __shfl_xor(v, off, 64);
            if (lane == 0) en[((size_t)b * Tq + tt) * Kq + k] = v;
        }
    }
}

// ---------------------------------------------------------------------------
// Kernel 4b: softmax over t per (b,k), in-place on en.  grid (B)
// ---------------------------------------------------------------------------
__global__ __launch_bounds__(256) void softmax_kernel(float* __restrict__ en)
{
    const int b = blockIdx.x;
    const int tid = threadIdx.x;
    const int lane = tid & 63, wv = tid >> 6;
    __shared__ float es[Tq * Kq];
    __shared__ float red[8];

    for (int o = tid; o < Tq * Kq; o += 256)
        es[o] = en[(size_t)b * Tq * Kq + o];
    __syncthreads();

    for (int k = 0; k < Kq; ++k) {
        float m = -1e30f;
        for (int tt = tid; tt < Tq; tt += 256) m = fmaxf(m, es[tt * Kq + k]);
        for (int off = 32; off > 0; off >>= 1) m = fmaxf(m, __shfl_xor(m, off, 64));
        if (lane == 0) red[wv] = m;
        __syncthreads();
        m = fmaxf(fmaxf(red[0], red[1]), fmaxf(red[2], red[3]));
        float ssum = 0.f;
        for (int tt = tid; tt < Tq; tt += 256) {
            const float e = __expf(es[tt * Kq + k] - m);
            es[tt * Kq + k] = e;
            ssum += e;
        }
        for (int off = 32; off > 0; off >>= 1) ssum += __shfl_xor(ssum, off, 64);
        if (lane == 0) red[4 + wv] = ssum;
        __syncthreads();
        const float inv = 1.f / (red[4] + red[5] + red[6] + red[7]);
        for (int tt = tid; tt < Tq; tt += 256) es[tt * Kq + k] *= inv;
        __syncthreads();
    }

    for (int o = tid; o < Tq * Kq; o += 256)
        en[(size_t)b * Tq * Kq + o] = es[o];
}

// ---------------------------------------------------------------------------
// Kernel 4c: pooled partials over 64-t chunks.  grid (8, B)
// ---------------------------------------------------------------------------
__global__ __launch_bounds__(256) void pooledp_kernel(
    const float* __restrict__ seq,
    const float* __restrict__ en,     // probs now
    float* __restrict__ partial)      // [B*8][1800]
{
    const int tc = blockIdx.x;
    const int b  = blockIdx.y;
    const int tid = threadIdx.x;
    const int lane = tid & 63, wv = tid >> 6;

    __shared__ float pr[64 * Kq];
    __shared__ float part[4][Kq * D2];   // 28.8 KB

    if (tid < 64 * Kq / 2) {
        pr[tid]       = en[((size_t)b * Tq + tc * 64) * Kq + tid];
        pr[tid + 192] = en[((size_t)b * Tq + tc * 64) * Kq + tid + 192];
    }
    __syncthreads();

    const float* seqb = seq + (size_t)b * Tq * D2;

    float pp[Kq][5];
    #pragma unroll
    for (int k = 0; k < Kq; ++k)
        #pragma unroll
        for (int q = 0; q < 5; ++q) pp[k][q] = 0.f;

    for (int s = 0; s < 16; ++s) {
        const int tl = s * 4 + wv;
        const int tt = tc * 64 + tl;
        float prr[Kq];
        #pragma unroll
        for (int k = 0; k < Kq; ++k) prr[k] = pr[tl * Kq + k];
        #pragma unroll
        for (int q = 0; q < 5; ++q) {
            const int d = lane + q * 64;
            const float sv = (d < D2) ? seqb[(size_t)tt * D2 + d] : 0.f;
            #pragma unroll
            for (int k = 0; k < Kq; ++k) pp[k][q] += prr[k] * sv;
        }
    }
    #pragma unroll
    for (int k = 0; k < Kq; ++k)
        #pragma unroll
        for (int q = 0; q < 5; ++q) {
            const int d = lane + q * 64;
            if (d < D2) part[wv][k * D2 + d] = pp[k][q];
        }
    __syncthreads();
    float* op = partial + ((size_t)b * 8 + tc) * (Kq * D2);
    for (int o = tid; o < Kq * D2; o += 256)
        op[o] = part[0][o] + part[1][o] + part[2][o] + part[3][o];
}

// ---------------------------------------------------------------------------
// Kernel 4d: final: pooled reduce -> topic -> logits -> softmax.  grid (B)
// ---------------------------------------------------------------------------
__global__ __launch_bounds__(256) void final_kernel(
    const float* __restrict__ partial,
    const float* __restrict__ Wtop,
    const float* __restrict__ btop,
    const float* __restrict__ Wout,
    const float* __restrict__ bout,
    float* __restrict__ outp)
{
    const int b = blockIdx.x;
    const int tid = threadIdx.x;
    __shared__ float pooled[Kq * D2];
    __shared__ float feats[Kq * THq];
    __shared__ float lsm[8];

    for (int o = tid; o < Kq * D2; o += 256) {
        float s = 0.f;
        #pragma unroll
        for (int c = 0; c < 8; ++c)
            s += partial[((size_t)b * 8 + c) * (Kq * D2) + o];
        pooled[o] = s;
    }
    __syncthreads();

    if (tid < Kq * THq) {
        const int k = tid / THq, hh = tid % THq;
        float acc = btop[tid];
        const float* wp = Wtop + (size_t)k * D2 * THq + hh;
        for (int d = 0; d < D2; ++d)
            acc += pooled[k * D2 + d] * wp[(size_t)d * THq];
        feats[tid] = fmaxf(acc, 0.f);
    }
    __syncthreads();

    if (tid < CLSq) {
        float acc = bout[tid];
        for (int f = 0; f < Kq * THq; ++f)
            acc += feats[f] * Wout[f * CLSq + tid];
        lsm[tid] = acc;
    }
    __syncthreads();
    if (tid < CLSq) {
        float m = lsm[0];
        for (int c = 1; c < CLSq; ++c) m = fmaxf(m, lsm[c]);
        float s = 0.f;
        for (int c = 0; c < CLSq; ++c) s += __expf(lsm[c] - m);
        outp[(size_t)b * CLSq + tid] = __expf(lsm[tid] - m) / s;
    }
}

// ---------------------------------------------------------------------------
// Kernel 5: reg = mean_b regbuf[b]  -> d_out[640]
// ---------------------------------------------------------------------------
__global__ void reg_final(const float* __restrict__ regbuf, float* __restrict__ outp)
{
    const int tid = threadIdx.x;   // 128 threads
    float v = regbuf[tid];
    for (int off = 32; off > 0; off >>= 1) v += __shfl_xor(v, off, 64);
    __shared__ float r2[2];
    if ((tid & 63) == 0) r2[tid >> 6] = v;
    __syncthreads();
    if (tid == 0) outp[Bq * CLSq] = (r2[0] + r2[1]) * (1.f / (float)Bq);
}

// ---------------------------------------------------------------------------
extern "C" void kernel_launch(void* const* d_in, const int* in_sizes, int n_in,
                              void* d_out, int out_size, void* d_ws, size_t ws_size,
                              hipStream_t stream)
{
    const float* x     = (const float*)d_in[0];
    const float* Wih_f = (const float*)d_in[1];
    const float* Whh_f = (const float*)d_in[2];
    const float* bih_f = (const float*)d_in[3];
    const float* bhh_f = (const float*)d_in[4];
    const float* Wih_b = (const float*)d_in[5];
    const float* Whh_b = (const float*)d_in[6];
    const float* bih_b = (const float*)d_in[7];
    const float* bhh_b = (const float*)d_in[8];
    const float* attn_context = (const float*)d_in[9];
    const float* Wattn = (const float*)d_in[10];
    const float* battn = (const float*)d_in[11];
    const float* Wtop  = (const float*)d_in[12];
    const float* btop  = (const float*)d_in[13];
    const float* Wout  = (const float*)d_in[14];
    const float* bout  = (const float*)d_in[15];
    float* outp = (float*)d_out;

    // fixed workspace layout (float units)
    float* ws       = (float*)d_ws;
    float* seqv     = ws;                                   // 19,660,800
    float* hstate   = seqv + (size_t)Bq * Tq * D2;          // 38,400
    float* ctxW     = hstate + (size_t)2 * Bq * Hq;         // 1,800
    float* context  = ctxW + Kq * D2;                       // 230,400
    float* regbuf   = context + (size_t)Bq * Kq * D2;       // 128
    float* normsq   = regbuf + Bq;                          // 768
    float* en       = normsq + Bq * Kq;                     // 393,216
    float* partial  = en + (size_t)Bq * Tq * Kq;            // 1,843,200
    __hip_bfloat16* xb16 = (__hip_bfloat16*)(partial + (size_t)Bq * 8 * Kq * D2); // 19,660,800 bf16
    __hip_bfloat16* Wb16 = xb16 + (size_t)Bq * Tq * Iq;     // 270,000 bf16
    float* gi_chunk = (float*)(Wb16 + (size_t)2 * G3 * Iq); // 115200*TCr fp32
    const size_t fixed_floats = (size_t)(gi_chunk - ws);

    // pick largest TCr in {256,128,64,32} that fits ws_size
    int tcShift = 5;
    for (int sh = 8; sh >= 5; --sh) {
        size_t need = (fixed_floats + (size_t)115200 * (1 << sh)) * 4;
        if (need <= ws_size) { tcShift = sh; break; }
    }
    const int TCr = 1 << tcShift;
    const int NL = Tq / TCr;

    // one-time bf16 casts (x, Wih_f, Wih_b)
    cast_bf16_kernel<<<dim3((Bq * Tq * Iq / 4 + 255) / 256), 256, 0, stream>>>(
        x, xb16, Bq * Tq * Iq / 4);
    cast_bf16_kernel<<<dim3((G3 * Iq / 4 + 255) / 256), 256, 0, stream>>>(
        Wih_f, Wb16, G3 * Iq / 4);
    cast_bf16_kernel<<<dim3((G3 * Iq / 4 + 255) / 256), 256, 0, stream>>>(
        Wih_b, Wb16 + (size_t)G3 * Iq, G3 * Iq / 4);

    for (int c = 0; c < NL; ++c) {
        const int t0f = c * TCr;
        const int t0b = Tq - TCr * (c + 1);
        gi_gemm_mfma<<<dim3(4, Bq * TCr / 128, 2), 256, 0, stream>>>(
            xb16, Wb16, bih_f, bih_b, gi_chunk, t0f, t0b, tcShift);
        gru_rec<<<dim3(2 * Bq), 512, 0, stream>>>(
            gi_chunk, Whh_f, bhh_f, Whh_b, bhh_b, hstate, seqv, c, tcShift);
    }

    ctxw_kernel<<<dim3((Kq * D2 + 255) / 256), 256, 0, stream>>>(
        attn_context, Wattn, battn, ctxW);
    ctx_compute<<<dim3(Bq, Kq), 256, 0, stream>>>(seqv, Wattn, ctxW, context, normsq);
    gram_kernel<<<dim3(Bq), 256, 0, stream>>>(context, normsq, regbuf);
    energy_kernel<<<dim3(8, Bq), 256, 0, stream>>>(seqv, context, en);
    softmax_kernel<<<dim3(Bq), 256, 0, stream>>>(en);
    pooledp_kernel<<<dim3(8, Bq), 256, 0, stream>>>(seqv, en, partial);
    final_kernel<<<dim3(Bq), 256, 0, stream>>>(partial, Wtop, btop, Wout, bout, outp);
    reg_final<<<dim3(1), 128, 0, stream>>>(regbuf, outp);
}